// Round 1
// baseline (105.232 us; speedup 1.0000x reference)
//
#include <hip/hip_runtime.h>
#include <hip/hip_bf16.h>
#include <stdint.h>

// Upsample2x(nearest) + Conv3x3(pad1) + bias, fused via the parity trick:
//   out[b,co,2r+py,2s+px] = bias[co] +
//     sum_{ky,kx in {0,1}, ci} weff[py,px][co][ky,kx,ci] * xpad[b, r+py+ky, s+px+kx, ci]
// where weff folds the 3x3 taps: even axis -> {w0, w1+w2}, odd axis -> {w0+w1, w2},
// and xpad is x in NHWC bf16 with a 1-pixel zero border ([8][34][34][512]).
// Each parity is an implicit GEMM: M=512(co) x N=8192(b,r,s) x K=2048(ky*2+kx,ci).

typedef __attribute__((ext_vector_type(8)))  __bf16 bf16x8;
typedef __attribute__((ext_vector_type(4)))  float  f32x4;
typedef __attribute__((ext_vector_type(4)))  int    int4v;

#define LDS_HALF 16384   // bytes: ldsA [128 rows][128B], ldsB same

__device__ __forceinline__ void async16(const void* g, void* l) {
  __builtin_amdgcn_global_load_lds(
      (const __attribute__((address_space(1))) void*)g,
      (__attribute__((address_space(3))) void*)l,
      16, 0, 0);
}

// ---------------------------------------------------------------------------
// prep_weff: weight [512][512][3][3] fp32 -> weff [4][512][4][512] bf16
//   weff[p=py*2+px][co][kk=ky*2+kx][ci] = sum of folded taps
__global__ void prep_weff(const float* __restrict__ w,
                          __hip_bfloat16* __restrict__ weff) {
  const int idx = blockIdx.x * 256 + threadIdx.x;   // = co*512 + ci, exact grid
  const int co = idx >> 9;
  const int ci = idx & 511;
  const float* wp = w + (size_t)idx * 9;            // [co][ci][3][3]
  float t[9];
#pragma unroll
  for (int i = 0; i < 9; ++i) t[i] = wp[i];
#pragma unroll
  for (int py = 0; py < 2; ++py) {
#pragma unroll
    for (int px = 0; px < 2; ++px) {
      const int p = py * 2 + px;
#pragma unroll
      for (int ky = 0; ky < 2; ++ky) {
        const int ulo = (ky == 0) ? 0 : (py == 0 ? 1 : 2);
        const int uhi = (ky == 0) ? (py == 0 ? 0 : 1) : 2;
#pragma unroll
        for (int kx = 0; kx < 2; ++kx) {
          const int vlo = (kx == 0) ? 0 : (px == 0 ? 1 : 2);
          const int vhi = (kx == 0) ? (px == 0 ? 0 : 1) : 2;
          float s = 0.f;
          for (int u = ulo; u <= uhi; ++u)
            for (int v = vlo; v <= vhi; ++v)
              s += t[u * 3 + v];
          const int kk = ky * 2 + kx;
          weff[(((size_t)p * 512 + co) * 4 + kk) * 512 + ci] = __float2bfloat16(s);
        }
      }
    }
  }
}

// ---------------------------------------------------------------------------
// prep_xpad: x [8][512][32][32] fp32 -> xpad [8][34][34][512] bf16 (border pre-zeroed
// by hipMemsetAsync). LDS transpose: block = (b, r, ci-tile of 64).
__global__ void prep_xpad(const float* __restrict__ x,
                          __hip_bfloat16* __restrict__ xpad) {
  const int blk = blockIdx.x;          // 8b * 32r * 8cib = 2048
  const int cib = blk & 7;
  const int r   = (blk >> 3) & 31;
  const int b   = blk >> 8;
  const int tid = threadIdx.x;
  __shared__ __align__(16) __hip_bfloat16 ldsT[32][80];  // [w][ci], stride 80 (2-way free on read)
  const int ci_l = tid >> 2;           // 0..63
  const int wq   = tid & 3;            // 8-wide w chunk
  const float* xp = x + (((size_t)(b * 512 + cib * 64 + ci_l) * 32 + r) * 32) + wq * 8;
  float4 v0 = *(const float4*)(xp);
  float4 v1 = *(const float4*)(xp + 4);
  const int wb = wq * 8;
  ldsT[wb + 0][ci_l] = __float2bfloat16(v0.x);
  ldsT[wb + 1][ci_l] = __float2bfloat16(v0.y);
  ldsT[wb + 2][ci_l] = __float2bfloat16(v0.z);
  ldsT[wb + 3][ci_l] = __float2bfloat16(v0.w);
  ldsT[wb + 4][ci_l] = __float2bfloat16(v1.x);
  ldsT[wb + 5][ci_l] = __float2bfloat16(v1.y);
  ldsT[wb + 6][ci_l] = __float2bfloat16(v1.z);
  ldsT[wb + 7][ci_l] = __float2bfloat16(v1.w);
  __syncthreads();
  const int w_o = tid >> 3;            // 0..31
  const int ch  = tid & 7;             // ci chunk of 8
  char* dst = (char*)xpad +
      ((((size_t)(b * 34 + (r + 1)) * 34) + (w_o + 1)) * 512 + cib * 64 + ch * 8) * 2;
  *(int4v*)dst = *(const int4v*)&ldsT[w_o][ch * 8];
}

// ---------------------------------------------------------------------------
// Main implicit GEMM. Tile BM=128(co) x BN=128(n) x BK=64. 4 waves, each 64x64.
// LDS rows are 128 B (exactly 32 banks) -> XOR slot-swizzle: LDS[row][slot]
// holds k-chunk (slot ^ (row&7)); applied on BOTH the global source (staging)
// and the ds_read address (rule: both-sides-or-neither with global_load_lds).
__global__ __launch_bounds__(256, 2) void upconv_gemm(
    const __hip_bfloat16* __restrict__ xpad,   // [8][34][34][512]
    const __hip_bfloat16* __restrict__ weff,   // [4][512][2048]
    const float* __restrict__ bias,
    float* __restrict__ out) {                 // [8][512][64][64]
  __shared__ __align__(16) char lds[2 * LDS_HALF];
  char* ldsA = lds;
  char* ldsB = lds + LDS_HALF;

  const int p  = blockIdx.y;           // parity
  const int py = p >> 1, px = p & 1;
  const int mt = blockIdx.x & 3;       // 4 co tiles
  const int nt = blockIdx.x >> 2;      // 64 n tiles
  const int co0 = mt << 7;
  const int n0  = nt << 7;
  const int b   = n0 >> 10;            // 128 | 1024 -> b fixed per tile
  const int r0  = (n0 & 1023) >> 5;    // tile covers rows r0..r0+3, full s=0..31

  const int tid  = threadIdx.x;
  const int lane = tid & 63;
  const int wv   = tid >> 6;
  const int wr   = wv >> 1, wc = wv & 1;

  // staging decomposition: per pass, thread covers row pass*32+(tid>>3), slot tid&7
  const int srow  = tid >> 3;          // 0..31
  const int sslot = tid & 7;
  const int cc8   = (sslot ^ (srow & 7)) << 3;   // swizzled k-chunk (elements)

  const __hip_bfloat16* wbase =
      weff + (size_t)p * 512 * 2048 + (size_t)(co0 + srow) * 2048 + cc8;

  f32x4 acc[4][4] = {};

  for (int kt = 0; kt < 32; ++kt) {
    const int k0  = kt << 6;
    const int kyx = k0 >> 9;           // (ky,kx) block: BK=64 never straddles
    const int ky  = kyx >> 1, kx = kyx & 1;
    const int ci  = (k0 & 511) + cc8;
    const int colI = srow + px + kx;   // 0..33, in-bounds of padded W
#pragma unroll
    for (int pass = 0; pass < 4; ++pass) {
      async16(wbase + (size_t)pass * 32 * 2048 + k0,
              ldsA + pass * 4096 + wv * 1024);
      const int rowI = r0 + pass + py + ky;  // 0..33, in-bounds of padded H
      const __hip_bfloat16* gb =
          xpad + ((size_t)((b * 34 + rowI) * 34 + colI)) * 512 + ci;
      async16(gb, ldsB + pass * 4096 + wv * 1024);
    }
    asm volatile("s_waitcnt vmcnt(0)" ::: "memory");
    __syncthreads();

#pragma unroll
    for (int ks = 0; ks < 2; ++ks) {
      bf16x8 af[4], bfr[4];
#pragma unroll
      for (int m = 0; m < 4; ++m) {
        const int row  = (wr << 6) + (m << 4) + (lane & 15);
        const int slot = ((ks << 2) + (lane >> 4)) ^ (row & 7);
        af[m] = *(const bf16x8*)(ldsA + row * 128 + slot * 16);
      }
#pragma unroll
      for (int nn = 0; nn < 4; ++nn) {
        const int row  = (wc << 6) + (nn << 4) + (lane & 15);
        const int slot = ((ks << 2) + (lane >> 4)) ^ (row & 7);
        bfr[nn] = *(const bf16x8*)(ldsB + row * 128 + slot * 16);
      }
#pragma unroll
      for (int m = 0; m < 4; ++m)
#pragma unroll
        for (int nn = 0; nn < 4; ++nn)
          acc[m][nn] = __builtin_amdgcn_mfma_f32_16x16x32_bf16(
              af[m], bfr[nn], acc[m][nn], 0, 0, 0);
    }
    __syncthreads();
  }

  // Epilogue: D layout row=(lane>>4)*4+j, col=lane&15 (measured m89).
#pragma unroll
  for (int m = 0; m < 4; ++m) {
    const int coB = co0 + (wr << 6) + (m << 4) + ((lane >> 4) << 2);
    float bv[4];
#pragma unroll
    for (int j = 0; j < 4; ++j) bv[j] = bias[coB + j];
#pragma unroll
    for (int nn = 0; nn < 4; ++nn) {
      const int n  = n0 + (wc << 6) + (nn << 4) + (lane & 15);
      const int rr = (n & 1023) >> 5;
      const int ss = n & 31;
      const int oh = (rr << 1) + py;
      const int ow = (ss << 1) + px;
#pragma unroll
      for (int j = 0; j < 4; ++j) {
        out[(((size_t)(b * 512 + coB + j) << 6) + oh) * 64 + ow] =
            acc[m][nn][j] + bv[j];
      }
    }
  }
}

// ---------------------------------------------------------------------------
extern "C" void kernel_launch(void* const* d_in, const int* in_sizes, int n_in,
                              void* d_out, int out_size, void* d_ws, size_t ws_size,
                              hipStream_t stream) {
  (void)in_sizes; (void)n_in; (void)out_size; (void)ws_size;
  const float* x  = (const float*)d_in[0];   // [8][512][32][32]
  const float* w  = (const float*)d_in[1];   // [512][512][3][3]
  const float* bs = (const float*)d_in[2];   // [512]
  float* out = (float*)d_out;                // [8][512][64][64]
  char* ws = (char*)d_ws;
  __hip_bfloat16* xpad = (__hip_bfloat16*)ws;                 // 9,467,904 B
  __hip_bfloat16* weff = (__hip_bfloat16*)(ws + (10u << 20)); // 8,388,608 B
  // zero border (interior fully rewritten each call -> deterministic)
  hipMemsetAsync(xpad, 0, (size_t)8 * 34 * 34 * 512 * 2, stream);
  prep_weff<<<dim3(1024), dim3(256), 0, stream>>>(w, weff);
  prep_xpad<<<dim3(2048), dim3(256), 0, stream>>>(x, xpad);
  upconv_gemm<<<dim3(256, 4), dim3(256), 0, stream>>>(xpad, weff, bs, out);
}